// Round 3
// baseline (378.041 us; speedup 1.0000x reference)
//
#include <hip/hip_runtime.h>

#define B_    2
#define CE_   32
#define D_    12
#define H_    256
#define W_    256
#define HW_   (H_*W_)
#define HID_  256
#define NPD   8
#define NPH   25
#define NPW   25
#define NP_   (B_*NPD*NPH*NPW)   // 10000
#define PJ    1805               // 5*19*19
#define NTILE 113                // ceil(1805/16)
#define PJPAD (NTILE*16)         // 1808
#define MBLK  157                // ceil(10000/64)

typedef __attribute__((ext_vector_type(8))) short s8v;     // 8 bf16
typedef __attribute__((ext_vector_type(4))) float f32x4;

__device__ __forceinline__ unsigned short f2bf(float f) {
    unsigned u = __float_as_uint(f);
    u += 0x7FFFu + ((u >> 16) & 1u);   // RNE
    return (unsigned short)(u >> 16);
}

// ---- W2 transpose->bf16 frag-friendly rows (blocks 0..112) + W1 frag pack (block 113)
__global__ __launch_bounds__(256) void k_pre(
    const float* __restrict__ W2, const float* __restrict__ W1,
    unsigned short* __restrict__ W2t, unsigned short* __restrict__ W1f)
{
    __shared__ unsigned short tile[16][264];
    const int t = threadIdx.x;
    if (blockIdx.x < 113) {
        const int j0 = blockIdx.x * 16;
        {
            const int jj = t & 15, kb = t >> 4;
            #pragma unroll
            for (int ki = 0; ki < 16; ki++) {
                const int k = kb*16 + ki;
                const int j = j0 + jj;
                const float v = (j < PJ) ? W2[(size_t)k*PJ + j] : 0.f;
                tile[jj][k] = f2bf(v);
            }
        }
        __syncthreads();
        const int jj = t >> 4, kb = t & 15;
        s8v a = *(const s8v*)&tile[jj][kb*16];
        s8v b = *(const s8v*)&tile[jj][kb*16+8];
        *(s8v*)&W2t[(size_t)(j0+jj)*HID_ + kb*16]     = a;
        *(s8v*)&W2t[(size_t)(j0+jj)*HID_ + kb*16 + 8] = b;
    } else {
        // W1f[((nt*4+q)*16+l)*8+e] = bf16(W1[(q*8+e)*HID + nt*16+l])
        for (int i = 0; i < 32; i++) {
            const int o = t*32 + i;
            const int e = o & 7, l = (o>>3)&15, q = (o>>7)&3, nt = o>>9;
            W1f[o] = f2bf(W1[(size_t)(q*8+e)*HID_ + nt*16 + l]);
        }
    }
}

// ---- packed 2x2 min/max of gt: M[bd][h][w] = (min<<8)|max over {h..h+1,w..w+1}
__global__ __launch_bounds__(256) void k_mm(
    const float* __restrict__ target, unsigned short* __restrict__ M)
{
    __shared__ float rows[5][256];
    const int t  = threadIdx.x;
    const int bd = blockIdx.x >> 6;          // b*D+d, 0..23
    const int h0 = (blockIdx.x & 63) << 2;
    const int b  = bd / D_, d = bd - b*D_;
    const size_t gbase = ((size_t)(b*4*D_) + d)*HW_;   // channel 0 = gt
    #pragma unroll
    for (int r = 0; r < 5; r++) {
        int h = h0 + r; if (h > 255) h = 255;
        rows[r][t] = target[gbase + h*W_ + t];
    }
    __syncthreads();
    const int w1 = (t < 255) ? t+1 : 255;
    #pragma unroll
    for (int r = 0; r < 4; r++) {
        const float g00 = rows[r][t],   g01 = rows[r][w1];
        const float g10 = rows[r+1][t], g11 = rows[r+1][w1];
        const float mn = fminf(fminf(g00,g01), fminf(g10,g11));
        const float mx = fmaxf(fmaxf(g00,g01), fmaxf(g10,g11));
        M[(size_t)bd*HW_ + (h0+r)*W_ + t] = (unsigned short)(((int)mn << 8) | (int)mx);
    }
}

// ---- fused: emb gather + MFMA GEMM1 + MFMA GEMM2 + sigmoid + mask + reduce
__global__ __launch_bounds__(256, 2) void k_main(
    const float* __restrict__ target, const float* __restrict__ pred,
    const unsigned short* __restrict__ W2t, const unsigned short* __restrict__ W1f,
    const float* __restrict__ b1, const float* __restrict__ b2,
    const unsigned short* __restrict__ M, double* __restrict__ accs)
{
    __shared__ unsigned short emb_f[2048];     // 4 KB  A-frags for GEMM1
    __shared__ unsigned short h_f[16384];      // 32 KB A-frags for GEMM2
    __shared__ unsigned short Bf[2][4096];     // 16 KB B-frag double buffer
    __shared__ int      val_s[64];
    __shared__ unsigned cp_s[64];
    __shared__ int      mb_s[64];
    __shared__ float    red_s[4][3];

    const int tid  = threadIdx.x;
    const int mt   = tid >> 6;       // wave = m-tile
    const int lane = tid & 63;
    const int quad = lane >> 4;
    const int l16  = lane & 15;
    const int m0   = blockIdx.x * 64;
    const int js   = blockIdx.y;
    const int t0   = (NTILE*js) >> 2;
    const int t1   = (NTILE*(js+1)) >> 2;

    // ---- phase 1: emb gather into A-frag LDS; patch metadata (threads<64)
    {
        const int m = tid >> 2, cg = tid & 3;
        int n = m0 + m; if (n >= NP_) n = NP_-1;
        int b = n / (NPD*NPH*NPW);
        int r = n - b*(NPD*NPH*NPW);
        int pd = r / (NPH*NPW); int r2 = r - pd*(NPH*NPW);
        int ph = r2 / NPW; int pw = r2 - ph*NPW;
        const int dc = 2+pd, hc = 21+9*ph, wc = 21+9*pw;
        const size_t pb = ((size_t)(b*CE_ + cg*8)*D_ + dc)*HW_ + (size_t)hc*W_ + wc;
        s8v ev;
        #pragma unroll
        for (int i = 0; i < 8; i++)
            ev[i] = (short)f2bf(pred[pb + (size_t)i*D_*HW_]);
        *(s8v*)&emb_f[(((m>>4)*4 + cg)*16 + (m&15))*8] = ev;
    }
    if (tid < 64) {
        int n = m0 + tid; const int inb = (n < NP_); if (!inb) n = NP_-1;
        int b = n / (NPD*NPH*NPW);
        int r = n - b*(NPD*NPH*NPW);
        int pd = r / (NPH*NPW); int r2 = r - pd*(NPH*NPW);
        int ph = r2 / NPW; int pw = r2 - ph*NPW;
        const int dc = 2+pd, hc = 21+9*ph, wc = 21+9*pw;
        const size_t tb = ((size_t)(b*4)*D_ + dc)*HW_ + (size_t)hc*W_ + wc;
        const float ctr = target[tb];
        const float a1 = target[tb + (size_t)1*D_*HW_];
        const float a2 = target[tb + (size_t)2*D_*HW_];
        const float a3 = target[tb + (size_t)3*D_*HW_];
        const int ci = (int)ctr;
        val_s[tid] = (ctr != 0.f) && (a1 != 0.f) && (a2 != 0.f) && (a3 != 0.f) && inb;
        cp_s[tid]  = (unsigned)((ci << 8) | ci);
        mb_s[tid]  = (b*D_ + pd)*HW_ + (2+9*ph)*W_ + (2+9*pw);
    }
    __syncthreads();

    // ---- GEMM1 via MFMA (K=32): h[m][k] written in GEMM2 A-frag order
    {
        const s8v ae = *(const s8v*)&emb_f[((mt*4+quad)*16 + l16)*8];
        #pragma unroll
        for (int nt = 0; nt < 16; nt++) {
            const s8v be = *(const s8v*)&W1f[((nt*4+quad)*16 + l16)*8];
            f32x4 c = {0.f,0.f,0.f,0.f};
            c = __builtin_amdgcn_mfma_f32_16x16x32_bf16(ae, be, c, 0, 0, 0);
            const float bias = b1[nt*16 + l16];
            const int kk = nt >> 1, q2 = ((nt&1) << 1) | (l16 >> 3), e = l16 & 7;
            #pragma unroll
            for (int reg = 0; reg < 4; reg++) {
                const float hv = fmaxf(c[reg] + bias, 0.f);
                h_f[((((mt*8+kk)*4) + q2)*16 + (quad*4+reg))*8 + e] = f2bf(hv);
            }
        }
    }
    // stage first B tile
    const int jjs = tid >> 4, khs = tid & 15;
    const int kks = khs >> 1, qAs = (khs & 1) << 1;
    {
        const unsigned short* src = W2t + (size_t)(t0*16 + jjs)*HID_ + khs*16;
        s8v s0 = *(const s8v*)src;
        s8v s1 = *(const s8v*)(src + 8);
        *(s8v*)&Bf[t0&1][(((kks*4)+qAs  )*16 + jjs)*8] = s0;
        *(s8v*)&Bf[t0&1][(((kks*4)+qAs+1)*16 + jjs)*8] = s1;
    }
    __syncthreads();

    // A-frags resident for whole j-loop
    s8v afr[8];
    #pragma unroll
    for (int kk = 0; kk < 8; kk++)
        afr[kk] = *(const s8v*)&h_f[((((mt*8+kk)*4) + quad)*16 + l16)*8];
    int vv[4]; unsigned cp[4]; int mb[4];
    #pragma unroll
    for (int r = 0; r < 4; r++) {
        const int p = mt*16 + quad*4 + r;
        vv[r] = val_s[p]; cp[r] = cp_s[p]; mb[r] = mb_s[p];
    }

    float num = 0.f, denp = 0.f, dent = 0.f;
    for (int tt = t0; tt < t1; tt++) {
        // prefetch next B tile into regs
        s8v s0, s1;
        const bool have = (tt+1 < t1);
        if (have) {
            const unsigned short* src = W2t + (size_t)((tt+1)*16 + jjs)*HID_ + khs*16;
            s0 = *(const s8v*)src;
            s1 = *(const s8v*)(src + 8);
        }
        // GEMM2 on current buffer
        const unsigned short* bb = &Bf[tt&1][0];
        f32x4 acc = {0.f,0.f,0.f,0.f};
        #pragma unroll
        for (int kk = 0; kk < 8; kk++) {
            const s8v bfr = *(const s8v*)&bb[(((kk*4)+quad)*16 + l16)*8];
            acc = __builtin_amdgcn_mfma_f32_16x16x32_bf16(afr[kk], bfr, acc, 0, 0, 0);
        }
        // epilogue: lane owns j = tt*16+l16, patches mt*16+quad*4+r
        const int j = tt*16 + l16;
        const bool jok = (j < PJ);
        float bj = 0.f; int offj = 0;
        if (jok) {
            const int dz = j/361, rj = j - dz*361;
            const int yy = rj/19, xx = rj - yy*19;
            bj = b2[j];
            offj = dz*HW_ + yy*(2*W_) + xx*2;
        }
        #pragma unroll
        for (int r = 0; r < 4; r++) {
            if (jok && vv[r]) {
                const unsigned mmv = M[mb[r] + offj];
                if (mmv >= 256u) {                 // min>0 => not ignored
                    const float tv = (mmv != cp[r]) ? 1.f : 0.f;
                    const float pv = 1.f / (1.f + __expf(-(acc[r] + bj)));
                    num  = fmaf(pv, tv, num);
                    denp = fmaf(pv, pv, denp);
                    dent += tv;                    // t^2 == t
                }
            }
        }
        if (have) {
            *(s8v*)&Bf[(tt+1)&1][(((kks*4)+qAs  )*16 + jjs)*8] = s0;
            *(s8v*)&Bf[(tt+1)&1][(((kks*4)+qAs+1)*16 + jjs)*8] = s1;
        }
        __syncthreads();
    }

    // reduce
    #pragma unroll
    for (int off = 32; off > 0; off >>= 1) {
        num  += __shfl_down(num,  off);
        denp += __shfl_down(denp, off);
        dent += __shfl_down(dent, off);
    }
    if (lane == 0) { red_s[mt][0] = num; red_s[mt][1] = denp; red_s[mt][2] = dent; }
    __syncthreads();
    if (tid == 0) {
        const float n_ = red_s[0][0]+red_s[1][0]+red_s[2][0]+red_s[3][0];
        const float p_ = red_s[0][1]+red_s[1][1]+red_s[2][1]+red_s[3][1];
        const float t_ = red_s[0][2]+red_s[1][2]+red_s[2][2]+red_s[3][2];
        atomicAdd(&accs[0], (double)n_);
        atomicAdd(&accs[1], (double)p_);
        atomicAdd(&accs[2], (double)t_);
    }
}

__global__ void k_final(const double* __restrict__ accs, float* __restrict__ out) {
    const double num = accs[0];
    const double den = accs[1] + accs[2];
    const double d   = den > 1e-6 ? den : 1e-6;
    out[0] = (float)(-2.0 * num / d);
}

extern "C" void kernel_launch(void* const* d_in, const int* in_sizes, int n_in,
                              void* d_out, int out_size, void* d_ws, size_t ws_size,
                              hipStream_t stream) {
    const float* target = (const float*)d_in[0];
    const float* pred   = (const float*)d_in[1];
    const float* W1     = (const float*)d_in[2];
    const float* b1     = (const float*)d_in[3];
    const float* W2     = (const float*)d_in[4];
    const float* b2     = (const float*)d_in[5];
    float* out = (float*)d_out;

    char* ws = (char*)d_ws;
    double*         accs = (double*)ws;                              // 64 B
    unsigned short* W2t  = (unsigned short*)(ws + 64);               // 1808*256*2 = 925,696
    unsigned short* W1f  = (unsigned short*)(ws + 64 + 925696);      // 16,384
    unsigned short* Mx   = (unsigned short*)(ws + 64 + 925696 + 16384); // 2*12*65536*2 = 3,145,728

    hipMemsetAsync(d_ws, 0, 64, stream);
    hipLaunchKernelGGL(k_pre,  dim3(114),     dim3(256), 0, stream, W2, W1, W2t, W1f);
    hipLaunchKernelGGL(k_mm,   dim3(1536),    dim3(256), 0, stream, target, Mx);
    hipLaunchKernelGGL(k_main, dim3(MBLK, 4), dim3(256), 0, stream,
                       target, pred, W2t, W1f, b1, b2, Mx, accs);
    hipLaunchKernelGGL(k_final, dim3(1), dim3(1), 0, stream, accs, out);
}